// Round 1
// baseline (34984.604 us; speedup 1.0000x reference)
//
#include <hip/hip_runtime.h>

#define BS 64
#define T_STEPS 512
#define D 1024   // D_IN == D_OUT

// ---------------- W_comb = W_rec @ W_in : C[o][j] = sum_i Wrec[o][i]*Win[i][j]
__global__ void wcomb_kernel(const float* __restrict__ Wrec,
                             const float* __restrict__ Win,
                             float* __restrict__ C) {
    __shared__ float As[16][17];
    __shared__ float Bs[16][17];
    const int tx = threadIdx.x, ty = threadIdx.y;
    const int o = blockIdx.y * 16 + ty;   // row of Wrec / row of C
    const int j = blockIdx.x * 16 + tx;   // col of Win / col of C
    float acc = 0.f;
    for (int k0 = 0; k0 < D; k0 += 16) {
        As[ty][tx] = Wrec[o * D + (k0 + tx)];
        Bs[ty][tx] = Win[(size_t)(k0 + ty) * D + j];
        __syncthreads();
#pragma unroll
        for (int kk = 0; kk < 16; ++kk)
            acc += As[ty][kk] * Bs[kk][tx];
        __syncthreads();
    }
    C[(size_t)o * D + j] = acc;
}

// ---------------- one recurrence step:
// s_out[b][o] = relu( sum_i s_in[b][i]*Wrec[o][i] + sum_j x[b][t][j]*Wcomb[o][j] )
__global__ void step_kernel(const float* __restrict__ x,      // [BS][T][D]
                            const float* __restrict__ Wrec,   // [D][D]
                            const float* __restrict__ Wcomb,  // [D][D]
                            const float* __restrict__ s_in,   // [BS][D]
                            float* __restrict__ s_out,        // [BS][D]
                            int t) {
    __shared__ float Ss[16][17];
    __shared__ float Ws[16][17];
    const int tx = threadIdx.x, ty = threadIdx.y;
    const int o = blockIdx.x * 16 + tx;   // output feature
    const int b = blockIdx.y * 16 + ty;   // batch
    float acc = 0.f;

    // part 1: s_in @ Wrec^T
    for (int k0 = 0; k0 < D; k0 += 16) {
        Ss[ty][tx] = s_in[(size_t)(blockIdx.y * 16 + ty) * D + k0 + tx];
        Ws[ty][tx] = Wrec[(size_t)(blockIdx.x * 16 + ty) * D + k0 + tx];
        __syncthreads();
#pragma unroll
        for (int kk = 0; kk < 16; ++kk)
            acc += Ss[ty][kk] * Ws[tx][kk];
        __syncthreads();
    }

    // part 2: x_t @ Wcomb^T
    const float* xt = x + (size_t)t * D;   // x[b][t][k] = xt[b*T*D + k]
    for (int k0 = 0; k0 < D; k0 += 16) {
        Ss[ty][tx] = xt[(size_t)(blockIdx.y * 16 + ty) * T_STEPS * D + k0 + tx];
        Ws[ty][tx] = Wcomb[(size_t)(blockIdx.x * 16 + ty) * D + k0 + tx];
        __syncthreads();
#pragma unroll
        for (int kk = 0; kk < 16; ++kk)
            acc += Ss[ty][kk] * Ws[tx][kk];
        __syncthreads();
    }

    s_out[(size_t)b * D + o] = fmaxf(acc, 0.f);
}

// ---------------- helpers
__global__ void zero_kernel(float* __restrict__ p, int n) {
    int i = blockIdx.x * 256 + threadIdx.x;
    if (i < n) p[i] = 0.f;
}

// write zeros everywhere except out[b][0][o] = s_final[b][o]; skip scratch range
__global__ void finalize_kernel(float* __restrict__ out,
                                const float* __restrict__ s_final,
                                long long scratch_lo, long long scratch_hi,
                                long long n) {
    long long i = (long long)blockIdx.x * 256 + threadIdx.x;
    if (i >= n) return;
    if (i >= scratch_lo && i < scratch_hi) return;   // wiped by second pass
    const int o = (int)(i & 1023);
    const int t = (int)((i >> 10) & 511);
    const int b = (int)(i >> 19);
    out[i] = (t == 0) ? s_final[b * 1024 + o] : 0.f;
}

extern "C" void kernel_launch(void* const* d_in, const int* in_sizes, int n_in,
                              void* d_out, int out_size, void* d_ws, size_t ws_size,
                              hipStream_t stream) {
    const float* x    = (const float*)d_in[0];  // [64][512][1024]
    const float* W_in = (const float*)d_in[1];  // [1024][1024]
    const float* W_rec= (const float*)d_in[2];  // [1024][1024]
    float* out = (float*)d_out;

    const size_t scratch_elems = (size_t)D * D + 2 * BS * D; // Wcomb + 2 state bufs
    float *Wcomb, *bufA, *bufB;
    long long scratch_lo = -1, scratch_hi = -1;
    if (ws_size >= scratch_elems * sizeof(float)) {
        Wcomb = (float*)d_ws;
    } else {
        // carve scratch out of a dead region of d_out (out[0, 1.., :] — zeros
        // in the final answer); zeroed by the second finalize pass.
        scratch_lo = 1024;
        scratch_hi = scratch_lo + (long long)scratch_elems;
        Wcomb = out + 1024;
    }
    bufA = Wcomb + (size_t)D * D;
    bufB = bufA + BS * D;

    // 1) W_comb = W_rec @ W_in
    wcomb_kernel<<<dim3(64, 64), dim3(16, 16), 0, stream>>>(W_rec, W_in, Wcomb);

    // 2) state0 = 0
    zero_kernel<<<(BS * D + 255) / 256, 256, 0, stream>>>(bufA, BS * D);

    // 3) 512 sequential steps (ping-pong state buffers)
    float* sin = bufA;
    float* sout = bufB;
    for (int t = 0; t < T_STEPS; ++t) {
        step_kernel<<<dim3(64, 4), dim3(16, 16), 0, stream>>>(x, W_rec, Wcomb, sin, sout, t);
        float* tmp = sin; sin = sout; sout = tmp;
    }
    // final state now in `sin`

    // 4) write output: zeros + final state at t==0 (skipping scratch range)
    const long long n = (long long)out_size;
    finalize_kernel<<<(int)((n + 255) / 256), 256, 0, stream>>>(out, sin, scratch_lo, scratch_hi, n);

    // 5) wipe scratch region if it lived in d_out
    if (scratch_lo >= 0) {
        zero_kernel<<<(int)((scratch_elems + 255) / 256), 256, 0, stream>>>(out + scratch_lo, (int)scratch_elems);
    }
}

// Round 3
// 17689.450 us; speedup vs baseline: 1.9777x; 1.9777x over previous
//
#include <hip/hip_runtime.h>
#include <hip/hip_cooperative_groups.h>

namespace cg = cooperative_groups;

typedef __attribute__((ext_vector_type(8))) short short8;
typedef __attribute__((ext_vector_type(4))) float f32x4;

#define D_DIM 1024
#define BS 64
#define TSTEPS 512

__device__ __forceinline__ unsigned short f2bf(float f){
    union { float f; unsigned u; } v; v.f = f;
    unsigned r = v.u + 0x7FFFu + ((v.u >> 16) & 1u);   // RNE
    return (unsigned short)(r >> 16);
}
__device__ __forceinline__ float bf2f(unsigned short h){
    union { unsigned u; float f; } v; v.u = ((unsigned)h) << 16;
    return v.f;
}
// split one float into hi/lo bf16 (double-bf16: ~17-bit mantissa)
__device__ __forceinline__ void split1(float f, unsigned short& h, unsigned short& l){
    h = f2bf(f);
    l = f2bf(f - bf2f(h));
}
__device__ __forceinline__ void split8(const float* __restrict__ p, short8& h8, short8& l8){
    float4 f0 = *(const float4*)p;
    float4 f1 = *(const float4*)(p + 4);
    float v[8] = {f0.x, f0.y, f0.z, f0.w, f1.x, f1.y, f1.z, f1.w};
#pragma unroll
    for (int i = 0; i < 8; ++i){
        unsigned short h, l; split1(v[i], h, l);
        h8[i] = (short)h; l8[i] = (short)l;
    }
}

// ---------------- ext[r][o] = sum_j x[r][j]*Win[o][j], r = b*512+t, fp32 out.
// hi/lo bf16 GEMM: acc = xh@Wh + xh@Wl + xl@Wh  (xl@Wl dropped, ~2^-18 rel)
__global__ __launch_bounds__(256) void ext_gemm(
    const float* __restrict__ x, const float* __restrict__ Win,
    float* __restrict__ ext)
{
    __shared__ unsigned short Ah[64 * 40];
    __shared__ unsigned short Al[64 * 40];
    const int tid = threadIdx.x;
    const int w = tid >> 6, L = tid & 63, lh = L & 15, q = L >> 4;
    const int m0 = blockIdx.y * 64;
    const int n0 = blockIdx.x * 64 + w * 16;
    const int r_st = tid >> 2, k8 = (tid & 3) * 8;

    f32x4 acc0 = {0,0,0,0}, acc1 = {0,0,0,0}, acc2 = {0,0,0,0}, acc3 = {0,0,0,0};

    for (int kc = 0; kc < 32; ++kc){
        short8 ash, asl;
        split8(x + (size_t)(m0 + r_st) * D_DIM + kc * 32 + k8, ash, asl);
        short8 bh, bl;
        split8(Win + (size_t)(n0 + lh) * D_DIM + kc * 32 + q * 8, bh, bl);
        *(short8*)&Ah[r_st * 40 + k8] = ash;
        *(short8*)&Al[r_st * 40 + k8] = asl;
        __syncthreads();
#pragma unroll
        for (int ms = 0; ms < 4; ++ms){
            short8 ah = *(const short8*)&Ah[(ms * 16 + lh) * 40 + q * 8];
            short8 al = *(const short8*)&Al[(ms * 16 + lh) * 40 + q * 8];
            f32x4* acc = (ms == 0) ? &acc0 : (ms == 1) ? &acc1 : (ms == 2) ? &acc2 : &acc3;
            *acc = __builtin_amdgcn_mfma_f32_16x16x32_bf16(ah, bh, *acc, 0, 0, 0);
            *acc = __builtin_amdgcn_mfma_f32_16x16x32_bf16(ah, bl, *acc, 0, 0, 0);
            *acc = __builtin_amdgcn_mfma_f32_16x16x32_bf16(al, bh, *acc, 0, 0, 0);
        }
        __syncthreads();
    }

    const int col = n0 + lh;
#pragma unroll
    for (int ms = 0; ms < 4; ++ms){
        f32x4 a = (ms == 0) ? acc0 : (ms == 1) ? acc1 : (ms == 2) ? acc2 : acc3;
#pragma unroll
        for (int r = 0; r < 4; ++r){
            int row = m0 + ms * 16 + q * 4 + r;
            ext[(size_t)row * D_DIM + col] = a[r];
        }
    }
}

// ---------------- persistent recurrence: v' = relu(v @ Wrec^T) + e_{t+1}
// state: 2 ping-pong pairs, each pair = hi plane + lo plane (bf16):
//   addr(p, h, b, o) = sb + p*spstr + h*shstr + b*sbstr + o   (ushort units)
__global__ __launch_bounds__(256, 1) void recurrent(
    const float* __restrict__ Wrec, const float* __restrict__ ext,
    unsigned short* __restrict__ sb, size_t spstr, size_t shstr, size_t sbstr)
{
    cg::grid_group grid = cg::this_grid();
    const int tid = threadIdx.x;
    const int w = tid >> 6, L = tid & 63, lh = L & 15, q = L >> 4;
    const int o0 = blockIdx.x * 16;   // 16 output features per wg
    const int b0 = w * 16;            // 16 batches per wave

    // W_rec hi/lo fragments in registers (256 VGPRs), fixed for all steps
    short8 wh[32], wl[32];
#pragma unroll
    for (int kc = 0; kc < 32; ++kc)
        split8(Wrec + (size_t)(o0 + lh) * D_DIM + kc * 32 + q * 8, wh[kc], wl[kc]);

    // init: v0 = e0. Read ALL e0 first, sync, then write pair 0 (which may
    // alias the ext t=0 region in the fallback layout).
    float ev[4];
#pragma unroll
    for (int i = 0; i < 4; ++i){
        int idx = tid * 4 + i;              // (b, oo) over 64x16
        int b = idx >> 4, oo = idx & 15;
        ev[i] = ext[(size_t)b * (TSTEPS * D_DIM) + (o0 + oo)];
    }
    asm volatile("s_waitcnt vmcnt(0)" ::: "memory");
    grid.sync();
#pragma unroll
    for (int i = 0; i < 4; ++i){
        int idx = tid * 4 + i;
        int b = idx >> 4, oo = idx & 15;
        unsigned short h, l; split1(ev[i], h, l);
        size_t a = (size_t)b * sbstr + (o0 + oo);
        sb[a] = h;
        sb[shstr + a] = l;
    }
    __threadfence();
    grid.sync();

    const size_t rdrow = (size_t)(b0 + lh) * sbstr + q * 8;

    for (int t = 0; t < TSTEPS; ++t){
        const int p = t & 1;
        const unsigned short* rh = sb + (size_t)p * spstr + rdrow;
        const unsigned short* rl = rh + shstr;
        f32x4 aHH = {0,0,0,0}, aHL = {0,0,0,0}, aLH = {0,0,0,0};
#pragma unroll 4
        for (int kc = 0; kc < 32; ++kc){
            short8 ah = *(const short8*)(rh + kc * 32);
            short8 al = *(const short8*)(rl + kc * 32);
            aHH = __builtin_amdgcn_mfma_f32_16x16x32_bf16(ah, wh[kc], aHH, 0, 0, 0);
            aHL = __builtin_amdgcn_mfma_f32_16x16x32_bf16(ah, wl[kc], aHL, 0, 0, 0);
            aLH = __builtin_amdgcn_mfma_f32_16x16x32_bf16(al, wh[kc], aLH, 0, 0, 0);
        }
        const int o = o0 + lh;
        const int te = t + 1;
        float e4[4] = {0.f, 0.f, 0.f, 0.f};
        if (te < TSTEPS){
#pragma unroll
            for (int r = 0; r < 4; ++r){
                int b = b0 + q * 4 + r;
                e4[r] = ext[(size_t)b * (TSTEPS * D_DIM) + (size_t)te * D_DIM + o];
            }
        }
        if (t == 0){
            // fallback layout: pair-1 writes alias the ext t=1 region; make
            // sure every wg's e_1 reads fully completed before any write.
            asm volatile("s_waitcnt vmcnt(0)" ::: "memory");
            grid.sync();
        }
        const size_t wbase = (size_t)(p ^ 1) * spstr;
#pragma unroll
        for (int r = 0; r < 4; ++r){
            int b = b0 + q * 4 + r;
            float f = fmaxf(aHH[r] + aHL[r] + aLH[r], 0.f) + e4[r];
            unsigned short h, l; split1(f, h, l);
            size_t a = wbase + (size_t)b * sbstr + o;
            sb[a] = h;
            sb[a + shstr] = l;
        }
        __threadfence();
        grid.sync();
    }
    // 512 steps -> final state in pair 0 (hi/lo)
}

// copy final state (pair 0) to a staging region that does not alias out[:,0,:]
__global__ __launch_bounds__(256) void stage_state(
    const unsigned short* __restrict__ sb, size_t shstr, size_t sbstr,
    unsigned short* __restrict__ st, size_t sthstr, size_t stbstr)
{
    int idx = blockIdx.x * 256 + threadIdx.x;   // 0..65535
    int b = idx >> 10, o = idx & 1023;
    st[(size_t)b * stbstr + o] = sb[(size_t)b * sbstr + o];
    st[sthstr + (size_t)b * stbstr + o] = sb[shstr + (size_t)b * sbstr + o];
}

__global__ __launch_bounds__(256) void finalize_state(
    float* __restrict__ out, const unsigned short* __restrict__ st,
    size_t sthstr, size_t stbstr)
{
    int idx = blockIdx.x * 256 + threadIdx.x;
    int b = idx >> 10, o = idx & 1023;
    float hi = bf2f(st[(size_t)b * stbstr + o]);
    float lo = bf2f(st[sthstr + (size_t)b * stbstr + o]);
    out[(size_t)b * (TSTEPS * D_DIM) + o] = hi + lo;
}

__global__ __launch_bounds__(256) void zero_rest(float* __restrict__ out)
{
    size_t i4 = (size_t)blockIdx.x * 256 + threadIdx.x;  // float4 index
    size_t f = i4 * 4;
    int t = (int)((f >> 10) & 511);
    if (t == 0) return;                                   // out[:,0,:] written by finalize
    *(float4*)(out + f) = make_float4(0.f, 0.f, 0.f, 0.f);
}

extern "C" void kernel_launch(void* const* d_in, const int* in_sizes, int n_in,
                              void* d_out, int out_size, void* d_ws, size_t ws_size,
                              hipStream_t stream) {
    const float* x    = (const float*)d_in[0];   // [64][512][1024]
    const float* W_in = (const float*)d_in[1];   // [1024][1024]
    const float* W_rec= (const float*)d_in[2];   // [1024][1024]
    float* out = (float*)d_out;
    unsigned short* out_us = (unsigned short*)d_out;

    // ext (fp32, [b][t][o]) always lives in d_out — it is dead space until the end.
    float* ext = out;

    // state: 2 pairs x (hi,lo) x [64][1024] bf16 = 512 KB; staging = 256 KB
    unsigned short* sb; size_t spstr, shstr, sbstr;
    unsigned short* st; size_t sthstr, stbstr;
    const size_t need_ws = (4 * 65536 + 2 * 65536) * sizeof(unsigned short);
    if (ws_size >= need_ws){
        sb = (unsigned short*)d_ws;
        spstr = 2 * 65536; shstr = 65536; sbstr = 1024;
        st = sb + 4 * 65536;
        sthstr = 65536; stbstr = 1024;
    } else {
        // carve from out: pair p lives over out[b][p] (consumed ext slices),
        // staging over out[b][2]. ushort addressing, 1048576 ushorts per batch.
        sb = out_us;
        spstr = 2048; shstr = 1024; sbstr = 1048576;
        st = out_us + 4096;
        sthstr = 1024; stbstr = 1048576;
    }

    // 1) ext = x @ W_in^T  (hi/lo bf16 MFMA, fp32 result)
    ext_gemm<<<dim3(16, 512), 256, 0, stream>>>(x, W_in, ext);

    // 2) persistent cooperative recurrence (64 wgs x 256 threads)
    void* cargs[] = { (void*)&W_rec, (void*)&ext, (void*)&sb,
                      (void*)&spstr, (void*)&shstr, (void*)&sbstr };
    hipLaunchCooperativeKernel((const void*)recurrent, dim3(64), dim3(256), cargs, 0, stream);

    // 3) stage final state away from out[:,0,:], write it, zero the rest
    stage_state<<<256, 256, 0, stream>>>(sb, shstr, sbstr, st, sthstr, stbstr);
    finalize_state<<<256, 256, 0, stream>>>(out, st, sthstr, stbstr);
    zero_rest<<<32768, 256, 0, stream>>>(out);
}

// Round 6
// 5598.711 us; speedup vs baseline: 6.2487x; 3.1596x over previous
//
#include <hip/hip_runtime.h>

typedef __attribute__((ext_vector_type(8))) short short8;
typedef __attribute__((ext_vector_type(4))) float f32x4;

#define D_DIM 1024
#define BS 64
#define TSTEPS 512

// Static device storage — avoids d_ws/d_out aliasing entirely. Rewritten from
// scratch on every kernel_launch call (deterministic across graph replays).
__device__ unsigned short g_w_hi[64 * 32 * 64 * 8];   // [fb][kc][lane][8] = 2 MB
__device__ unsigned short g_w_lo[64 * 32 * 64 * 8];   // 2 MB
__device__ unsigned short g_s_hi[2][BS * D_DIM];      // state hi plane, ping-pong
__device__ unsigned short g_s_lo[2][BS * D_DIM];      // state lo plane

__device__ __forceinline__ unsigned short f2bf(float f){
    union { float f; unsigned u; } v; v.f = f;
    unsigned r = v.u + 0x7FFFu + ((v.u >> 16) & 1u);   // RNE
    return (unsigned short)(r >> 16);
}
__device__ __forceinline__ float bf2f(unsigned short h){
    union { unsigned u; float f; } v; v.u = ((unsigned)h) << 16;
    return v.f;
}
__device__ __forceinline__ void split1(float f, unsigned short& h, unsigned short& l){
    h = f2bf(f);
    l = f2bf(f - bf2f(h));
}
__device__ __forceinline__ void split8(const float* __restrict__ p, short8& h8, short8& l8){
    float4 f0 = *(const float4*)p;
    float4 f1 = *(const float4*)(p + 4);
    float v[8] = {f0.x, f0.y, f0.z, f0.w, f1.x, f1.y, f1.z, f1.w};
#pragma unroll
    for (int i = 0; i < 8; ++i){
        unsigned short h, l; split1(v[i], h, l);
        h8[i] = (short)h; l8[i] = (short)l;
    }
}

// ---------------- ext[r][o] = sum_j x[r][j]*Win[o][j], fp32, r = b*512+t.
// Byte-identical to the R3-round PASSING version (hi/lo bf16 MFMA).
__global__ __launch_bounds__(256) void ext_gemm(
    const float* __restrict__ x, const float* __restrict__ Win,
    float* __restrict__ ext)
{
    __shared__ unsigned short Ah[64 * 40];
    __shared__ unsigned short Al[64 * 40];
    const int tid = threadIdx.x;
    const int w = tid >> 6, L = tid & 63, lh = L & 15, q = L >> 4;
    const int m0 = blockIdx.y * 64;
    const int n0 = blockIdx.x * 64 + w * 16;
    const int r_st = tid >> 2, k8 = (tid & 3) * 8;

    f32x4 acc0 = {0,0,0,0}, acc1 = {0,0,0,0}, acc2 = {0,0,0,0}, acc3 = {0,0,0,0};

    for (int kc = 0; kc < 32; ++kc){
        short8 ash, asl;
        split8(x + (size_t)(m0 + r_st) * D_DIM + kc * 32 + k8, ash, asl);
        short8 bh, bl;
        split8(Win + (size_t)(n0 + lh) * D_DIM + kc * 32 + q * 8, bh, bl);
        *(short8*)&Ah[r_st * 40 + k8] = ash;
        *(short8*)&Al[r_st * 40 + k8] = asl;
        __syncthreads();
#pragma unroll
        for (int ms = 0; ms < 4; ++ms){
            short8 ah = *(const short8*)&Ah[(ms * 16 + lh) * 40 + q * 8];
            short8 al = *(const short8*)&Al[(ms * 16 + lh) * 40 + q * 8];
            f32x4* acc = (ms == 0) ? &acc0 : (ms == 1) ? &acc1 : (ms == 2) ? &acc2 : &acc3;
            *acc = __builtin_amdgcn_mfma_f32_16x16x32_bf16(ah, bh, *acc, 0, 0, 0);
            *acc = __builtin_amdgcn_mfma_f32_16x16x32_bf16(ah, bl, *acc, 0, 0, 0);
            *acc = __builtin_amdgcn_mfma_f32_16x16x32_bf16(al, bh, *acc, 0, 0, 0);
        }
        __syncthreads();
    }

    const int col = n0 + lh;
#pragma unroll
    for (int ms = 0; ms < 4; ++ms){
        f32x4 a = (ms == 0) ? acc0 : (ms == 1) ? acc1 : (ms == 2) ? acc2 : acc3;
#pragma unroll
        for (int r = 0; r < 4; ++r){
            int row = m0 + ms * 16 + q * 4 + r;
            ext[(size_t)row * D_DIM + col] = a[r];
        }
    }
}

// ---------------- pack W_rec into MFMA-fragment-ordered hi/lo bf16 arrays.
// fb = feature block (16 features), lane: lh = feature-in-block, q = k-chunk.
__global__ __launch_bounds__(64) void prep_w(const float* __restrict__ Wrec)
{
    const int L = threadIdx.x, lh = L & 15, q = L >> 4;
    const int fb = blockIdx.x;                        // 0..63
    for (int kc = 0; kc < 32; ++kc){
        short8 h8, l8;
        split8(Wrec + (size_t)(fb * 16 + lh) * D_DIM + kc * 32 + q * 8, h8, l8);
        *(short8*)&g_w_hi[(((size_t)fb * 32 + kc) * 64 + L) * 8] = h8;
        *(short8*)&g_w_lo[(((size_t)fb * 32 + kc) * 64 + L) * 8] = l8;
    }
}

// ---------------- v0 = e0 into state plane 0
__global__ __launch_bounds__(256) void init_state(const float* __restrict__ ext)
{
    int idx = blockIdx.x * 256 + threadIdx.x;         // 0..65535 = b*1024+o
    int b = idx >> 10, o = idx & 1023;
    unsigned short h, l;
    split1(ext[(size_t)b * (TSTEPS * D_DIM) + o], h, l);
    g_s_hi[0][idx] = h;
    g_s_lo[0][idx] = l;
}

// ---------------- one step: v' = relu(v @ Wrec^T) + e_{t_next}  (e=0 if t_next>=512)
// Grid 256 wgs x 64 thr: wg j -> features (j>>2)*16.., batches (j&3)*16..
__global__ __launch_bounds__(64) void step_kernel(
    const float* __restrict__ ext, int t_next, int p)
{
    const int L = threadIdx.x, lh = L & 15, q = L >> 4;
    const int j = blockIdx.x;
    const int fb = j >> 2, b0 = (j & 3) * 16;
    const int o0 = fb * 16;

    const unsigned short* sh = &g_s_hi[p][(b0 + lh) * D_DIM + q * 8];
    const unsigned short* sl = &g_s_lo[p][(b0 + lh) * D_DIM + q * 8];
    const unsigned short* wh = &g_w_hi[((size_t)fb * 32 * 64 + L) * 8];
    const unsigned short* wl = &g_w_lo[((size_t)fb * 32 * 64 + L) * 8];

    f32x4 aHH = {0,0,0,0}, aHL = {0,0,0,0}, aLH = {0,0,0,0};
#pragma unroll 8
    for (int kc = 0; kc < 32; ++kc){
        short8 ah = *(const short8*)(sh + kc * 32);
        short8 al = *(const short8*)(sl + kc * 32);
        short8 bh = *(const short8*)(wh + (size_t)kc * 512);
        short8 bl = *(const short8*)(wl + (size_t)kc * 512);
        aHH = __builtin_amdgcn_mfma_f32_16x16x32_bf16(ah, bh, aHH, 0, 0, 0);
        aHL = __builtin_amdgcn_mfma_f32_16x16x32_bf16(ah, bl, aHL, 0, 0, 0);
        aLH = __builtin_amdgcn_mfma_f32_16x16x32_bf16(al, bh, aLH, 0, 0, 0);
    }

    const int o = o0 + lh;
    const int wp = p ^ 1;
#pragma unroll
    for (int r = 0; r < 4; ++r){
        int b = b0 + q * 4 + r;
        float f = fmaxf(aHH[r] + aHL[r] + aLH[r], 0.f);
        if (t_next < TSTEPS)
            f += ext[(size_t)b * (TSTEPS * D_DIM) + (size_t)t_next * D_DIM + o];
        unsigned short h, l; split1(f, h, l);
        g_s_hi[wp][b * D_DIM + o] = h;
        g_s_lo[wp][b * D_DIM + o] = l;
    }
}

// ---------------- out[b][0][o] = final state (plane 0); rest zeroed separately
__global__ __launch_bounds__(256) void finalize_state(float* __restrict__ out)
{
    int idx = blockIdx.x * 256 + threadIdx.x;         // 0..65535
    int b = idx >> 10, o = idx & 1023;
    out[(size_t)b * (TSTEPS * D_DIM) + o] = bf2f(g_s_hi[0][idx]) + bf2f(g_s_lo[0][idx]);
}

__global__ __launch_bounds__(256) void zero_rest(float* __restrict__ out)
{
    size_t i4 = (size_t)blockIdx.x * 256 + threadIdx.x;  // float4 index
    size_t f = i4 * 4;
    int t = (int)((f >> 10) & 511);
    if (t == 0) return;                                   // out[:,0,:] kept
    *(float4*)(out + f) = make_float4(0.f, 0.f, 0.f, 0.f);
}

extern "C" void kernel_launch(void* const* d_in, const int* in_sizes, int n_in,
                              void* d_out, int out_size, void* d_ws, size_t ws_size,
                              hipStream_t stream) {
    const float* x    = (const float*)d_in[0];   // [64][512][1024]
    const float* W_in = (const float*)d_in[1];   // [1024][1024]
    const float* W_rec= (const float*)d_in[2];   // [1024][1024]
    float* out = (float*)d_out;

    // ext (fp32, [b][t][o]) lives in d_out — dead space until the end.
    float* ext = out;

    // 1) pack weights (fragment-ordered bf16 hi/lo) + input projection
    prep_w<<<64, 64, 0, stream>>>(W_rec);
    ext_gemm<<<dim3(16, 512), 256, 0, stream>>>(x, W_in, ext);

    // 2) v0 = e0
    init_state<<<256, 256, 0, stream>>>(ext);

    // 3) 512 sequential step dispatches (inter-dispatch ordering = free sync).
    //    step k: reads plane k&1, writes plane (k&1)^1, adds e_{k+1} if k<511.
    for (int k = 0; k < TSTEPS; ++k)
        step_kernel<<<256, 64, 0, stream>>>(ext, k + 1, k & 1);
    // final state in plane 0 (step 511 writes (511&1)^1 = 0)

    // 4) write out[:,0,:] from final state, then zero the rest
    finalize_state<<<256, 256, 0, stream>>>(out);
    zero_rest<<<32768, 256, 0, stream>>>(out);
}